// Round 7
// baseline (171.731 us; speedup 1.0000x reference)
//
#include <hip/hip_runtime.h>
#include <hip/hip_bf16.h>

typedef __bf16 bf16x8 __attribute__((ext_vector_type(8)));
typedef float f32x4 __attribute__((ext_vector_type(4)));
typedef float f32x16 __attribute__((ext_vector_type(16)));
typedef int int4v __attribute__((ext_vector_type(4)));
typedef unsigned int uint4v __attribute__((ext_vector_type(4)));
typedef unsigned short u16x8 __attribute__((ext_vector_type(8)));

#define N_NODES 8192
#define D_FEAT 128

// Round-6 diagnosis: fused layer = 75us because EVERY block read the full
// 2 MiB Bpk -> 512 MiB/layer of B traffic through L3 (~10 TB/s observed
// ceiling). This round: block = 128 rows x 128 cols x K-quarter (split-K4
// across blocks) -> B = 128 MiB/layer; XCD-swizzle pins each kq's 512 KiB
// B-quarter into one XCD's L2. Partial C/deg to ws + combine kernel.
// Bit layout / sigma / Bpk formulas byte-identical to verified round 6.

// ---------------------------------------------------------------------------
__device__ __forceinline__ bf16x8 unpack_byte(unsigned dword, int sh) {
  unsigned P = ((dword >> sh) & 0xFFu) * 0x8001u;
  uint4v c;
  c[0] = (P & 0x10001u) * 0x3F80u;
  c[1] = ((P >> 2) & 0x10001u) * 0x3F80u;
  c[2] = ((P >> 4) & 0x10001u) * 0x3F80u;
  c[3] = ((P >> 6) & 0x10001u) * 0x3F80u;
  return __builtin_bit_cast(bf16x8, c);
}

// ---------------------------------------------------------------------------
// Bpk fragment build (verified rounds 2-6). Fragment f = kk*256 + ng*64 + l
// holds, at element e: F[sigma(kk*16 + (l>>5)*8 + e)][ng*32 + (l&31)],
// sigma(p) = 256*(p>>8) + 32*((p>>3)&7) + 4*(p&7) + ((p>>6)&3)
__device__ __forceinline__ void bpk32_store(const float* __restrict__ src,
                                            unsigned short* __restrict__ Bpk,
                                            int W) {
  const int kk = W >> 8;
  const int ng = (W >> 6) & 3;
  const int l = W & 63;
  const int d = ng * 32 + (l & 31);
  const int p0 = kk * 16 + (l >> 5) * 8;
  const int n0 = (p0 >> 8) * 256 + ((p0 >> 3) & 7) * 32 + ((p0 >> 6) & 3);
  u16x8 pk;
#pragma unroll
  for (int e = 0; e < 8; ++e) {
    __bf16 v = (__bf16)src[(long)(n0 + 4 * e) * D_FEAT + d];
    pk[e] = __builtin_bit_cast(unsigned short, v);
  }
  *(u16x8*)(Bpk + (long)W * 8) = pk;
}

__global__ __launch_bounds__(256) void bpk_build32_kernel(
    const float* __restrict__ src, unsigned short* __restrict__ Bpk) {
  bpk32_store(src, Bpk, blockIdx.x * 256 + threadIdx.x);
}

// ---------------------------------------------------------------------------
// Fused pack+GEMM split-K block. Grid 256 = 64 rowblk x 4 kq (XCD-swizzled).
// Block: rows [m0, m0+128), all 128 cols, K-ints [kq*2048, +2048) in 8 chunks
// of 256 ints. 8 waves = 2 m-halves x 4 ng. Per chunk: each wave ballots its
// 16 rows into LDS bits (double-buffered), then GEMMs 32 MFMAs from bits x
// L2-resident Bpk quarter. Writes partial C (f32) and partial deg (u16).
__global__ __launch_bounds__(512, 2) void fused_split_kernel(
    const int* __restrict__ adj, const unsigned short* __restrict__ Bpk,
    float* __restrict__ pC, unsigned short* __restrict__ degP) {
  __shared__ unsigned bitsL[2][1536];  // [buf][row*12 + slot0..7], 12 KiB

  const int tid = threadIdx.x;
  const int lane = tid & 63;
  const int w = tid >> 6;        // 0..7
  const int l31 = lane & 31;
  const int lh = lane >> 5;
  const int lh8 = lh * 8;
  const int mh = w >> 2;         // m-half (64 rows)
  const int ng = w & 3;          // 32-col group

  // XCD swizzle: xcd = bx&7 -> kq = xcd>>1 (each kq pinned to 2 XCDs).
  const int bx = blockIdx.x;
  const int xcd = bx & 7;
  const int kq = xcd >> 1;                         // 0..3
  const int rowblk = (bx >> 3) + ((xcd & 1) << 5); // 0..63
  const int m0 = rowblk * 128;

  // Ballot rows for this wave: m0 + w*16 + i, i in [0,16).
  const int* aR = adj + ((long)(m0 + w * 16) << 13) + (long)kq * 2048;

  int4v av[16];
  int cnt[16];
#pragma unroll
  for (int i = 0; i < 16; ++i) cnt[i] = 0;

  f32x16 accA = {0.f, 0.f, 0.f, 0.f, 0.f, 0.f, 0.f, 0.f,
                 0.f, 0.f, 0.f, 0.f, 0.f, 0.f, 0.f, 0.f};
  f32x16 accB = accA;

#define LOAD_CHUNK(C)                                                        \
  {                                                                          \
    _Pragma("unroll") for (int i = 0; i < 16; ++i)                           \
        av[i] = *((const int4v*)(aR + ((long)i << 13)) + (C)*64 + lane);     \
  }

  // Ballot layout (verified r6): slot s = 2e+h of row holds bit b <->
  // adjacency col (within 256-chunk) = 128h + 4b + e.
#define DO_BALLOT(BUF)                                                       \
  {                                                                          \
    const int e_ = lane >> 1;                                                \
    _Pragma("unroll") for (int i = 0; i < 16; ++i) {                         \
      unsigned long long b0 = __ballot(av[i][0] != 0);                       \
      unsigned long long b1 = __ballot(av[i][1] != 0);                       \
      unsigned long long b2 = __ballot(av[i][2] != 0);                       \
      unsigned long long b3 = __ballot(av[i][3] != 0);                       \
      cnt[i] += __popcll(b0) + __popcll(b1) + __popcll(b2) + __popcll(b3);   \
      unsigned long long bsel = b0;                                          \
      if (e_ == 1) bsel = b1;                                                \
      if (e_ == 2) bsel = b2;                                                \
      if (e_ == 3) bsel = b3;                                                \
      unsigned dv = (lane & 1) ? (unsigned)(bsel >> 32) : (unsigned)bsel;    \
      if (lane < 8) bitsL[BUF][(w * 16 + i) * 12 + lane] = dv;               \
    }                                                                        \
  }

  // GEMM one chunk (verified r6 consumption): kk = (kq*8+C)*16 + kh2*8 + kkl,
  // slot = kh2*4 + (kkl>>1), sh = lh*8 + 16*(kkl&1); bv_j <-> kk0+j.
#define GEMM_HALF(C, BUF, KH2)                                               \
  {                                                                          \
    const bf16x8* bp = (const bf16x8*)Bpk +                                  \
        (((long)((kq * 8 + (C)) * 16 + (KH2)*8)) << 8) + ng * 64 + lane;     \
    bf16x8 bv0 = bp[0], bv1 = bp[256], bv2 = bp[512], bv3 = bp[768];         \
    bf16x8 bv4 = bp[1024], bv5 = bp[1280], bv6 = bp[1536], bv7 = bp[1792];   \
    const uint4v* bq = (const uint4v*)(&bitsL[BUF][0]);                      \
    uint4v qA = bq[(mh * 64 + l31) * 3 + (KH2)];                             \
    uint4v qB = bq[(mh * 64 + 32 + l31) * 3 + (KH2)];                        \
    accA = __builtin_amdgcn_mfma_f32_32x32x16_bf16(unpack_byte(qA[0], lh8),  \
                                                   bv0, accA, 0, 0, 0);      \
    accB = __builtin_amdgcn_mfma_f32_32x32x16_bf16(unpack_byte(qB[0], lh8),  \
                                                   bv0, accB, 0, 0, 0);      \
    accA = __builtin_amdgcn_mfma_f32_32x32x16_bf16(                          \
        unpack_byte(qA[0], lh8 + 16), bv1, accA, 0, 0, 0);                   \
    accB = __builtin_amdgcn_mfma_f32_32x32x16_bf16(                          \
        unpack_byte(qB[0], lh8 + 16), bv1, accB, 0, 0, 0);                   \
    accA = __builtin_amdgcn_mfma_f32_32x32x16_bf16(unpack_byte(qA[1], lh8),  \
                                                   bv2, accA, 0, 0, 0);      \
    accB = __builtin_amdgcn_mfma_f32_32x32x16_bf16(unpack_byte(qB[1], lh8),  \
                                                   bv2, accB, 0, 0, 0);      \
    accA = __builtin_amdgcn_mfma_f32_32x32x16_bf16(                          \
        unpack_byte(qA[1], lh8 + 16), bv3, accA, 0, 0, 0);                   \
    accB = __builtin_amdgcn_mfma_f32_32x32x16_bf16(                          \
        unpack_byte(qB[1], lh8 + 16), bv3, accB, 0, 0, 0);                   \
    accA = __builtin_amdgcn_mfma_f32_32x32x16_bf16(unpack_byte(qA[2], lh8),  \
                                                   bv4, accA, 0, 0, 0);      \
    accB = __builtin_amdgcn_mfma_f32_32x32x16_bf16(unpack_byte(qB[2], lh8),  \
                                                   bv4, accB, 0, 0, 0);      \
    accA = __builtin_amdgcn_mfma_f32_32x32x16_bf16(                          \
        unpack_byte(qA[2], lh8 + 16), bv5, accA, 0, 0, 0);                   \
    accB = __builtin_amdgcn_mfma_f32_32x32x16_bf16(                          \
        unpack_byte(qB[2], lh8 + 16), bv5, accB, 0, 0, 0);                   \
    accA = __builtin_amdgcn_mfma_f32_32x32x16_bf16(unpack_byte(qA[3], lh8),  \
                                                   bv6, accA, 0, 0, 0);      \
    accB = __builtin_amdgcn_mfma_f32_32x32x16_bf16(unpack_byte(qB[3], lh8),  \
                                                   bv6, accB, 0, 0, 0);      \
    accA = __builtin_amdgcn_mfma_f32_32x32x16_bf16(                          \
        unpack_byte(qA[3], lh8 + 16), bv7, accA, 0, 0, 0);                   \
    accB = __builtin_amdgcn_mfma_f32_32x32x16_bf16(                          \
        unpack_byte(qB[3], lh8 + 16), bv7, accB, 0, 0, 0);                   \
  }

  // Prologue: ballot chunk 0, issue chunk 1.
  LOAD_CHUNK(0)
  DO_BALLOT(0)
  LOAD_CHUNK(1)
  __syncthreads();

  for (int c = 0; c < 8; ++c) {
    if (c + 1 < 8) DO_BALLOT((c + 1) & 1)   // consume av (chunk c+1)
    if (c + 2 < 8) LOAD_CHUNK(c + 2)        // refill av
    GEMM_HALF(c, c & 1, 0)
    GEMM_HALF(c, c & 1, 1)
    __syncthreads();
  }
#undef GEMM_HALF
#undef DO_BALLOT
#undef LOAD_CHUNK

  // Partial degrees (wave-uniform scalars).
  if (lane == 0) {
#pragma unroll
    for (int i = 0; i < 16; ++i)
      degP[kq * N_NODES + m0 + w * 16 + i] = (unsigned short)cnt[i];
  }

  // Partial C (no deg divide here). C/D layout (m101): col = ng*32 + l31,
  // row = m0 + mh*64 + mt*32 + (r&3) + 8*(r>>2) + 4*lh.
  float* base = pC + ((long)kq << 20);
#pragma unroll
  for (int r = 0; r < 16; ++r) {
    const int rr = (r & 3) + 8 * (r >> 2) + 4 * lh;
    base[(long)(m0 + mh * 64 + rr) * D_FEAT + ng * 32 + l31] = accA[r];
    base[(long)(m0 + mh * 64 + 32 + rr) * D_FEAT + ng * 32 + l31] = accB[r];
  }
}

// ---------------------------------------------------------------------------
// Combine: out = deg>0 ? (sum of 4 K-quarter partials)/deg : fin.
__global__ __launch_bounds__(256) void combine_kernel(
    const float* __restrict__ pC, const unsigned short* __restrict__ degP,
    const float* __restrict__ fin, float* __restrict__ fout) {
  const int g = blockIdx.x * 256 + threadIdx.x;  // 0..262143 (f32x4 units)
  const int row = g >> 5;
  const f32x4* P = (const f32x4*)pC;
  f32x4 s = P[g] + P[262144 + g] + P[524288 + g] + P[786432 + g];
  const int dg = (int)degP[row] + degP[N_NODES + row] + degP[2 * N_NODES + row] +
                 degP[3 * N_NODES + row];
  f32x4 o;
  if (dg > 0) {
    o = s * (1.0f / (float)dg);
  } else {
    o = ((const f32x4*)fin)[g];
  }
  ((f32x4*)fout)[g] = o;
}

// ---------------------------------------------------------------------------
// Fallback path (round-1 verified), used only if ws too small.
__global__ __launch_bounds__(256) void transpose_cast_kernel(
    const float* __restrict__ src, unsigned short* __restrict__ dst) {
  __shared__ float tile[64][129];
  const int t = threadIdx.x;
  const int nbase = blockIdx.x * 64;
#pragma unroll
  for (int i = 0; i < 32; ++i) {
    int idx = t + i * 256;
    int nl = idx >> 7;
    int d = idx & 127;
    tile[nl][d] = src[(long)(nbase + nl) * D_FEAT + d];
  }
  __syncthreads();
#pragma unroll
  for (int i = 0; i < 32; ++i) {
    int idx = t + i * 256;
    int d = idx >> 6;
    int nl = idx & 63;
    __bf16 b = (__bf16)tile[nl][d];
    dst[(long)d * N_NODES + nbase + nl] = __builtin_bit_cast(unsigned short, b);
  }
}

__global__ __launch_bounds__(512) void layer_kernel_direct(
    const int* __restrict__ adj, const unsigned short* __restrict__ BT,
    const float* __restrict__ fin, float* __restrict__ fout) {
  const int tid = threadIdx.x;
  const int lane = tid & 63;
  const int w = tid >> 6;
  const int m0 = blockIdx.x * 32 + (w >> 2) * 16;
  const int n0 = (w & 3) * 32;
  const int lr = lane & 15;
  const int kc = lane >> 4;

  const int4v* ap = (const int4v*)(adj + (long)(m0 + lr) * N_NODES + kc * 8);
  const bf16x8* bp0 = (const bf16x8*)(BT + (long)(n0 + lr) * N_NODES + kc * 8);
  const bf16x8* bp1 =
      (const bf16x8*)(BT + (long)(n0 + 16 + lr) * N_NODES + kc * 8);

  f32x4 acc0 = {0.f, 0.f, 0.f, 0.f};
  f32x4 acc1 = {0.f, 0.f, 0.f, 0.f};
  int degv = 0;

#pragma unroll 4
  for (int k = 0; k < N_NODES; k += 32) {
    int4v alo = ap[0];
    int4v ahi = ap[1];
    bf16x8 b0 = bp0[0];
    bf16x8 b1 = bp1[0];
    ap += 8;
    bp0 += 4;
    bp1 += 4;
    unsigned short u[8];
    u[0] = alo[0] ? 0x3F80 : 0;
    u[1] = alo[1] ? 0x3F80 : 0;
    u[2] = alo[2] ? 0x3F80 : 0;
    u[3] = alo[3] ? 0x3F80 : 0;
    u[4] = ahi[0] ? 0x3F80 : 0;
    u[5] = ahi[1] ? 0x3F80 : 0;
    u[6] = ahi[2] ? 0x3F80 : 0;
    u[7] = ahi[3] ? 0x3F80 : 0;
    degv += alo[0] + alo[1] + alo[2] + alo[3] + ahi[0] + ahi[1] + ahi[2] +
            ahi[3];
    bf16x8 a;
    memcpy(&a, u, 16);
    acc0 = __builtin_amdgcn_mfma_f32_16x16x32_bf16(a, b0, acc0, 0, 0, 0);
    acc1 = __builtin_amdgcn_mfma_f32_16x16x32_bf16(a, b1, acc1, 0, 0, 0);
  }

  degv += __shfl_xor(degv, 16);
  degv += __shfl_xor(degv, 32);
  int dgv[4];
#pragma unroll
  for (int j = 0; j < 4; ++j) dgv[j] = __shfl(degv, kc * 4 + j);

#pragma unroll
  for (int t = 0; t < 2; ++t) {
    const f32x4 acc = t ? acc1 : acc0;
    const int col = n0 + t * 16 + lr;
#pragma unroll
    for (int j = 0; j < 4; ++j) {
      const long off = (long)(m0 + kc * 4 + j) * D_FEAT + col;
      fout[off] = dgv[j] > 0 ? acc[j] * (1.0f / (float)dgv[j]) : fin[off];
    }
  }
}

// ---------------------------------------------------------------------------
extern "C" void kernel_launch(void* const* d_in, const int* in_sizes, int n_in,
                              void* d_out, int out_size, void* d_ws,
                              size_t ws_size, hipStream_t stream) {
  const float* features = (const float*)d_in[0];
  const int* adj = (const int*)d_in[1];
  float* out = (float*)d_out;
  const long NN = (long)N_NODES * N_NODES;

  const size_t PC_BYTES = 4ul * N_NODES * D_FEAT * 4;     // 16 MiB
  const size_t DEG_BYTES = 4ul * N_NODES * 2;             // 64 KiB
  const size_t BPK_BYTES = (size_t)D_FEAT * N_NODES * 2;  // 2 MiB
  const size_t NEED = PC_BYTES + DEG_BYTES + BPK_BYTES;   // == verified bound

  if (ws_size >= NEED) {
    float* pC = (float*)d_ws;
    unsigned short* degP = (unsigned short*)((char*)d_ws + PC_BYTES);
    unsigned short* Bpk =
        (unsigned short*)((char*)d_ws + PC_BYTES + DEG_BYTES);

    // Layer 1
    bpk_build32_kernel<<<512, 256, 0, stream>>>(features, Bpk);
    fused_split_kernel<<<256, 512, 0, stream>>>(adj, Bpk, pC, degP);
    combine_kernel<<<1024, 256, 0, stream>>>(pC, degP, features, out);
    // Layer 2
    bpk_build32_kernel<<<512, 256, 0, stream>>>(out, Bpk);
    fused_split_kernel<<<256, 512, 0, stream>>>(adj + NN, Bpk, pC, degP);
    combine_kernel<<<1024, 256, 0, stream>>>(pC, degP, out, out);
  } else {
    // Fallback: round-1 verified path (needs only 2 MiB ws)
    unsigned short* BTw = (unsigned short*)d_ws;
    transpose_cast_kernel<<<N_NODES / 64, 256, 0, stream>>>(features, BTw);
    layer_kernel_direct<<<N_NODES / 32, 512, 0, stream>>>(adj, BTw, features,
                                                          out);
    transpose_cast_kernel<<<N_NODES / 64, 256, 0, stream>>>(out, BTw);
    layer_kernel_direct<<<N_NODES / 32, 512, 0, stream>>>(adj + NN, BTw, out,
                                                          out);
  }
}